// Round 16
// baseline (1101.985 us; speedup 1.0000x reference)
//
#include <hip/hip_runtime.h>
#include <hip/hip_cooperative_groups.h>
#include <math.h>

namespace cg = cooperative_groups;

// Capsule dynamic routing, B=64, R=4608, C=32, Din=Dout=16, 3 iters.
// b-logits are linear in v -> keep only vsum; u_hat recomputed per pass via
// mfma_f32_32x32x16_f16 (K=16==Din, A=Wfrag, B=xfrag -> D[(c,o)][b]).
//
// Round-16: ONE cooperative kernel (256 blocks x 1024 thr = 1/CU). All
// intra-kernel memory optimizations since r7 were null; the only wins were
// structural. Remaining ~40us attributed to the 11 serialized dispatches
// (tail-drain + launch each) + x re-staging + xa round-trip. Fused: x-tile
// converted straight into (persistent) LDS once, 3 passes + reductions
// separated by grid.sync(); wp produced in pass 1. Fallback = round-14 path.

#define B_    64
#define R_    4608
#define C_    32
#define RB    36
#define NBLK  (R_ / RB)      // 128
#define SELEM 32768          // 512 * 64

typedef _Float16 half8  __attribute__((ext_vector_type(8)));
typedef _Float16 half4v __attribute__((ext_vector_type(4)));
typedef _Float16 half2v __attribute__((ext_vector_type(2)));
typedef float    f32x16 __attribute__((ext_vector_type(16)));

__device__ __forceinline__ void gload_lds16(const void* g, void* l) {
    __builtin_amdgcn_global_load_lds(
        (const __attribute__((address_space(1))) void*)g,
        (__attribute__((address_space(3))) void*)l, 16, 0, 0);
}

// ============================ fused cooperative kernel =====================
__global__ __launch_bounds__(1024, 4)
void caps_fused(const float* __restrict__ x, const float* __restrict__ Wg,
                _Float16* __restrict__ wp, float* __restrict__ s_part,
                float* __restrict__ s2, float* __restrict__ vsumT,
                float* __restrict__ out)
{
    cg::grid_group grid = cg::this_grid();

    __shared__ _Float16 xalds[RB * 512];      // 36 KB, persists across passes
    __shared__ float tc_lds[2][32][33];       // 8.25 KB
    __shared__ float sq_lds[16][64];          // 4 KB (reduceB)

    const int D     = blockIdx.x;
    const int xcd   = D & 7;
    const int slot  = D >> 3;
    const int chunk = (slot >> 1) * 8 + xcd;  // 0..127 (XCD pairing, bijective)
    const int bh    = slot & 1;

    const int tid  = threadIdx.x;
    const int lane = tid & 63;
    const int wv   = tid >> 6;                // 0..15 = N-tile
    const int h    = lane >> 5;
    const int l31  = lane & 31;
    const int r0   = chunk * RB;
    const int bg   = bh * 32 + l31;

    // ---- phase 0: x tile -> swizzled LDS, read f32 directly (no xa) ----
    // logical layout data[P], P = rloc*1024 + b_loc*32 + i*2 (bytes);
    // stored at f(P) = P ^ (((P>>7)&7)<<4) (same involution the reader uses).
    {
        const float* xbase = x + (size_t)(bh * 32) * (R_ * 16);
        for (int i = tid; i < RB * 32 * 4; i += 1024) {   // 4608 16B-chunks
            const int b_   = i / (RB * 4);
            const int rem  = i - b_ * (RB * 4);
            const int rloc = rem >> 2;
            const int part = rem & 3;
            const float4 v = *(const float4*)(xbase + (size_t)b_ * (R_ * 16)
                                              + (size_t)(r0 + rloc) * 16 + part * 4);
            half4v f;
            f[0] = (_Float16)v.x; f[1] = (_Float16)v.y;
            f[2] = (_Float16)v.z; f[3] = (_Float16)v.w;
            const int P = rloc * 1024 + b_ * 32 + part * 8;
            const int A = P ^ (((P >> 7) & 7) << 4);
            *(half4v*)((char*)xalds + A) = f;
        }
    }
    __syncthreads();

    const int avoff = ((l31 << 5) + (h << 4)) ^ (((l31 >> 2) & 7) << 4);
    const int c_ = 2 * wv + (l31 >> 4);
    const int o_ = l31 & 15;
    const size_t wstride = 16 * 64 * 8;       // f16 per r

    f32x16 zf;
#pragma unroll
    for (int k = 0; k < 16; ++k) zf[k] = 0.f;

    // ---- pass 1: fused W f32 fragment gather + MFMA + wp write ----
    {
        f32x16 sacc = zf;
        half8 bc;
        {
            const float* ws_ = Wg + (((size_t)r0 * 32 + c_) * 16 + 8 * h) * 16 + o_;
#pragma unroll
            for (int e = 0; e < 8; ++e) bc[e] = (_Float16)ws_[e * 16];
        }
#pragma unroll 1
        for (int t = 0; t < RB; ++t) {
            const half8 av = *(const half8*)((const char*)xalds + t * 1024 + avoff);
            sacc = __builtin_amdgcn_mfma_f32_32x32x16_f16(bc, av, sacc, 0, 0, 0);
            if (bh == 0)
                *(half8*)(wp + (((size_t)(r0 + t) * 16 + wv) * 64 + lane) * 8) = bc;
            if (t + 1 < RB) {
                const float* ws_ = Wg + (((size_t)(r0 + t + 1) * 32 + c_) * 16 + 8 * h) * 16 + o_;
#pragma unroll
                for (int e = 0; e < 8; ++e) bc[e] = (_Float16)ws_[e * 16];
            }
        }
        float* sp = s_part + ((size_t)chunk << 15);
#pragma unroll
        for (int e = 0; e < 16; ++e) {
            const int g = wv * 32 + (e & 3) + 8 * (e >> 2) + 4 * h;
            sp[(size_t)g * 64 + bg] = sacc[e] * 0.03125f;
        }
    }

    // ---- 3x { reduceA ; reduceB+squash(mode) ; [pass] } ----
#pragma unroll 1
    for (int mode = 0; mode < 3; ++mode) {
        __threadfence();
        grid.sync();
        // reduce A: 128 partials -> 8 (exactly 1 task per thread in grid)
        {
            const int gId = D * 1024 + tid;           // 0..262143
            const int pg  = gId >> 15;                // 0..7
            const int e   = gId & (SELEM - 1);
            const float* p0 = s_part + (size_t)pg * 16 * SELEM + e;
            float a = 0.f;
#pragma unroll
            for (int p = 0; p < 16; ++p) a += p0[(size_t)p * SELEM];
            s2[(size_t)pg * SELEM + e] = a;
        }
        __threadfence();
        grid.sync();
        // reduce B + squash: 32 blocks, thread = (c=D, o=tid>>6, b=tid&63)
        if (D < 32) {
            float a = 0.f;
#pragma unroll
            for (int p = 0; p < 8; ++p) a += s2[(size_t)p * SELEM + D * 1024 + tid];
            sq_lds[tid >> 6][tid & 63] = a * a;
            __syncthreads();
            float sq = 0.f;
#pragma unroll
            for (int o = 0; o < 16; ++o) sq += sq_lds[o][tid & 63];
            const float n = sqrtf(sq);
            const float v = a * (sq / (1.0f + sq) / (n + 1e-8f));
            if (mode == 0)      vsumT[D * 1024 + tid] = v;
            else if (mode == 1) vsumT[D * 1024 + tid] += v;
            else                out[(size_t)(tid & 63) * 512 + D * 16 + (tid >> 6)] = v;
        }
        if (mode == 2) break;
        __threadfence();
        grid.sync();

        // ---- pass 2 / 3 (round-14 verified 2-r batched body) ----
        {
            half2v vh[8];
#pragma unroll
            for (int e = 0; e < 16; ++e) {
                const int g = wv * 32 + (e & 3) + 8 * (e >> 2) + 4 * h;
                vh[e >> 1][e & 1] = (_Float16)vsumT[(size_t)g * 64 + bg];
            }
            f32x16 sacc = zf;
            const _Float16* wpb = wp + ((size_t)wv * 64 + lane) * 8;
            half8 bc0 = *(const half8*)(wpb + (size_t)(r0    ) * wstride);
            half8 bc1 = *(const half8*)(wpb + (size_t)(r0 + 1) * wstride);

#pragma unroll 1
            for (int t = 0; t < RB; t += 2) {
                const half8 av0 = *(const half8*)((const char*)xalds + (t    ) * 1024 + avoff);
                const half8 av1 = *(const half8*)((const char*)xalds + (t + 1) * 1024 + avoff);

                const f32x16 u0 = __builtin_amdgcn_mfma_f32_32x32x16_f16(bc0, av0, zf, 0, 0, 0);
                const f32x16 u1 = __builtin_amdgcn_mfma_f32_32x32x16_f16(bc1, av1, zf, 0, 0, 0);

                const int tn = (t + 2 < RB) ? (t + 2) : t;
                bc0 = *(const half8*)(wpb + (size_t)(r0 + tn    ) * wstride);
                bc1 = *(const half8*)(wpb + (size_t)(r0 + tn + 1) * wstride);

                {
                    float a0 = 0.f, a1 = 0.f, b0 = 0.f, b1 = 0.f;
#pragma unroll
                    for (int e2 = 0; e2 < 4; ++e2) {
                        a0 += u0[2 * e2]         * (float)vh[e2][0];
                        a0 += u0[2 * e2 + 1]     * (float)vh[e2][1];
                        a1 += u0[8 + 2 * e2]     * (float)vh[4 + e2][0];
                        a1 += u0[8 + 2 * e2 + 1] * (float)vh[4 + e2][1];
                        b0 += u1[2 * e2]         * (float)vh[e2][0];
                        b0 += u1[2 * e2 + 1]     * (float)vh[e2][1];
                        b1 += u1[8 + 2 * e2]     * (float)vh[4 + e2][0];
                        b1 += u1[8 + 2 * e2 + 1] * (float)vh[4 + e2][1];
                    }
                    a0 += __shfl_xor(a0, 32);
                    a1 += __shfl_xor(a1, 32);
                    b0 += __shfl_xor(b0, 32);
                    b1 += __shfl_xor(b1, 32);
                    if (h == 0) {
                        tc_lds[0][2 * wv    ][l31] = a0;
                        tc_lds[0][2 * wv + 1][l31] = a1;
                        tc_lds[1][2 * wv    ][l31] = b0;
                        tc_lds[1][2 * wv + 1][l31] = b1;
                    }
                }
                __syncthreads();

                {
                    const int rr   = tid >> 9;
                    const int tid5 = tid & 511;
                    const int a_   = tid5 & 15;
                    const int b2   = tid5 >> 4;
                    const float tA = tc_lds[rr][2 * a_][b2];
                    const float tB = tc_lds[rr][2 * a_ + 1][b2];
                    float m = fmaxf(tA, tB);
                    m = fmaxf(m, __shfl_xor(m, 1));
                    m = fmaxf(m, __shfl_xor(m, 2));
                    m = fmaxf(m, __shfl_xor(m, 4));
                    m = fmaxf(m, __shfl_xor(m, 8));
                    const float eA = __expf(tA - m);
                    const float eB = __expf(tB - m);
                    float zs = eA + eB;
                    zs += __shfl_xor(zs, 1);
                    zs += __shfl_xor(zs, 2);
                    zs += __shfl_xor(zs, 4);
                    zs += __shfl_xor(zs, 8);
                    const float inv = 1.0f / zs;
                    tc_lds[rr][2 * a_][b2]     = eA * inv;
                    tc_lds[rr][2 * a_ + 1][b2] = eB * inv;
                }
                __syncthreads();

                {
                    const float c00 = tc_lds[0][2 * wv    ][l31];
                    const float c01 = tc_lds[0][2 * wv + 1][l31];
                    const float c10 = tc_lds[1][2 * wv    ][l31];
                    const float c11 = tc_lds[1][2 * wv + 1][l31];
#pragma unroll
                    for (int e = 0; e < 8; ++e)
                        sacc[e] += c00 * u0[e] + c10 * u1[e];
#pragma unroll
                    for (int e = 8; e < 16; ++e)
                        sacc[e] += c01 * u0[e] + c11 * u1[e];
                }
            }

            float* sp = s_part + ((size_t)chunk << 15);
#pragma unroll
            for (int e = 0; e < 16; ++e) {
                const int g = wv * 32 + (e & 3) + 8 * (e >> 2) + 4 * h;
                sp[(size_t)g * 64 + bg] = sacc[e];
            }
        }
    }
}

// ===================== fallback: round-14 multi-kernel path ================
__global__ __launch_bounds__(512)
void caps_prep(const float* __restrict__ x, _Float16* __restrict__ xa)
{
    __shared__ _Float16 tl[8][64][16];
    const int t  = threadIdx.x;
    const int r0 = blockIdx.x * 8;
    {
        const int b = t >> 3, j8 = t & 7;
        const float4* xs = (const float4*)(x + ((size_t)b * R_ + r0 + j8) * 16);
        const float4 A = xs[0], Bv = xs[1], Cv = xs[2], Dv = xs[3];
        half8 lo, hi;
        lo[0]=(_Float16)A.x;  lo[1]=(_Float16)A.y;  lo[2]=(_Float16)A.z;  lo[3]=(_Float16)A.w;
        lo[4]=(_Float16)Bv.x; lo[5]=(_Float16)Bv.y; lo[6]=(_Float16)Bv.z; lo[7]=(_Float16)Bv.w;
        hi[0]=(_Float16)Cv.x; hi[1]=(_Float16)Cv.y; hi[2]=(_Float16)Cv.z; hi[3]=(_Float16)Cv.w;
        hi[4]=(_Float16)Dv.x; hi[5]=(_Float16)Dv.y; hi[6]=(_Float16)Dv.z; hi[7]=(_Float16)Dv.w;
        *(half8*)&tl[j8][b][0] = lo;
        *(half8*)&tl[j8][b][8] = hi;
    }
    __syncthreads();
    {
        const int rl = t >> 6, q = t & 63;
        _Float16* dst = xa + (size_t)(r0 + rl) * 1024 + q * 16;
        *(half8*)dst       = *(const half8*)&tl[rl][q][0];
        *(half8*)(dst + 8) = *(const half8*)&tl[rl][q][8];
    }
}

template<bool FIRST>
__global__ __launch_bounds__(1024, 4)
void caps_mfma(const _Float16* __restrict__ xa, const float* __restrict__ Wg,
               _Float16* __restrict__ wp, const float* __restrict__ vsumT,
               float* __restrict__ sdst)
{
    __shared__ _Float16 xalds[RB * 512];
    __shared__ float tc_lds[2][32][33];

    const int D     = blockIdx.x;
    const int xcd   = D & 7;
    const int slot  = D >> 3;
    const int chunk = (slot >> 1) * 8 + xcd;
    const int bh    = slot & 1;

    const int tid  = threadIdx.x;
    const int lane = tid & 63;
    const int wv   = tid >> 6;
    const int h    = lane >> 5;
    const int l31  = lane & 31;
    const int r0   = chunk * RB;
    const int bg   = bh * 32 + l31;

    {
        const int slx = (lane << 4) ^ (((lane >> 3) & 7) << 4);
        for (int t = wv; t < RB; t += 16) {
            const char* src = (const char*)xa + (size_t)(r0 + t) * 2048 + bh * 1024 + slx;
            gload_lds16(src, (char*)xalds + t * 1024);
        }
    }

    f32x16 sacc, zf;
#pragma unroll
    for (int k = 0; k < 16; ++k) { sacc[k] = 0.f; zf[k] = 0.f; }

    half2v vh[8];
    if (!FIRST) {
#pragma unroll
        for (int e = 0; e < 16; ++e) {
            const int g = wv * 32 + (e & 3) + 8 * (e >> 2) + 4 * h;
            vh[e >> 1][e & 1] = (_Float16)vsumT[(size_t)g * 64 + bg];
        }
    }

    asm volatile("s_waitcnt vmcnt(0)" ::: "memory");
    __syncthreads();

    const int avoff = ((l31 << 5) + (h << 4)) ^ (((l31 >> 2) & 7) << 4);
    const int c_ = 2 * wv + (l31 >> 4);
    const int o_ = l31 & 15;
#define WGATHER(dst, r)                                                           \
    do {                                                                          \
        const float* ws_ = Wg + (((size_t)(r) * 32 + c_) * 16 + 8 * h) * 16 + o_; \
        _Pragma("unroll")                                                         \
        for (int e_ = 0; e_ < 8; ++e_) dst[e_] = (_Float16)ws_[e_ * 16];          \
    } while (0)

    const size_t wstride = 16 * 64 * 8;

    if (FIRST) {
        half8 bc;
        WGATHER(bc, r0);
#pragma unroll 1
        for (int t = 0; t < RB; ++t) {
            const half8 av = *(const half8*)((const char*)xalds + t * 1024 + avoff);
            sacc = __builtin_amdgcn_mfma_f32_32x32x16_f16(bc, av, sacc, 0, 0, 0);
            if (bh == 0)
                *(half8*)(wp + (((size_t)(r0 + t) * 16 + wv) * 64 + lane) * 8) = bc;
            if (t + 1 < RB) WGATHER(bc, r0 + t + 1);
        }
    } else {
        const _Float16* wpb = wp + ((size_t)wv * 64 + lane) * 8;
        half8 bc0 = *(const half8*)(wpb + (size_t)(r0    ) * wstride);
        half8 bc1 = *(const half8*)(wpb + (size_t)(r0 + 1) * wstride);

#pragma unroll 1
        for (int t = 0; t < RB; t += 2) {
            const half8 av0 = *(const half8*)((const char*)xalds + (t    ) * 1024 + avoff);
            const half8 av1 = *(const half8*)((const char*)xalds + (t + 1) * 1024 + avoff);

            const f32x16 u0 = __builtin_amdgcn_mfma_f32_32x32x16_f16(bc0, av0, zf, 0, 0, 0);
            const f32x16 u1 = __builtin_amdgcn_mfma_f32_32x32x16_f16(bc1, av1, zf, 0, 0, 0);

            const int tn = (t + 2 < RB) ? (t + 2) : t;
            bc0 = *(const half8*)(wpb + (size_t)(r0 + tn    ) * wstride);
            bc1 = *(const half8*)(wpb + (size_t)(r0 + tn + 1) * wstride);

            {
                float a0 = 0.f, a1 = 0.f, b0 = 0.f, b1 = 0.f;
#pragma unroll
                for (int e2 = 0; e2 < 4; ++e2) {
                    a0 += u0[2 * e2]         * (float)vh[e2][0];
                    a0 += u0[2 * e2 + 1]     * (float)vh[e2][1];
                    a1 += u0[8 + 2 * e2]     * (float)vh[4 + e2][0];
                    a1 += u0[8 + 2 * e2 + 1] * (float)vh[4 + e2][1];
                    b0 += u1[2 * e2]         * (float)vh[e2][0];
                    b0 += u1[2 * e2 + 1]     * (float)vh[e2][1];
                    b1 += u1[8 + 2 * e2]     * (float)vh[4 + e2][0];
                    b1 += u1[8 + 2 * e2 + 1] * (float)vh[4 + e2][1];
                }
                a0 += __shfl_xor(a0, 32);
                a1 += __shfl_xor(a1, 32);
                b0 += __shfl_xor(b0, 32);
                b1 += __shfl_xor(b1, 32);
                if (h == 0) {
                    tc_lds[0][2 * wv    ][l31] = a0;
                    tc_lds[0][2 * wv + 1][l31] = a1;
                    tc_lds[1][2 * wv    ][l31] = b0;
                    tc_lds[1][2 * wv + 1][l31] = b1;
                }
            }
            __syncthreads();

            {
                const int rr   = tid >> 9;
                const int tid5 = tid & 511;
                const int a_   = tid5 & 15;
                const int b2   = tid5 >> 4;
                const float tA = tc_lds[rr][2 * a_][b2];
                const float tB = tc_lds[rr][2 * a_ + 1][b2];
                float m = fmaxf(tA, tB);
                m = fmaxf(m, __shfl_xor(m, 1));
                m = fmaxf(m, __shfl_xor(m, 2));
                m = fmaxf(m, __shfl_xor(m, 4));
                m = fmaxf(m, __shfl_xor(m, 8));
                const float eA = __expf(tA - m);
                const float eB = __expf(tB - m);
                float zs = eA + eB;
                zs += __shfl_xor(zs, 1);
                zs += __shfl_xor(zs, 2);
                zs += __shfl_xor(zs, 4);
                zs += __shfl_xor(zs, 8);
                const float inv = 1.0f / zs;
                tc_lds[rr][2 * a_][b2]     = eA * inv;
                tc_lds[rr][2 * a_ + 1][b2] = eB * inv;
            }
            __syncthreads();

            {
                const float c00 = tc_lds[0][2 * wv    ][l31];
                const float c01 = tc_lds[0][2 * wv + 1][l31];
                const float c10 = tc_lds[1][2 * wv    ][l31];
                const float c11 = tc_lds[1][2 * wv + 1][l31];
#pragma unroll
                for (int e = 0; e < 8; ++e)
                    sacc[e] += c00 * u0[e] + c10 * u1[e];
#pragma unroll
                for (int e = 8; e < 16; ++e)
                    sacc[e] += c01 * u0[e] + c11 * u1[e];
            }
        }
    }
#undef WGATHER

    const float scale = FIRST ? 0.03125f : 1.0f;
    float* sp = sdst + ((size_t)chunk << 15);
#pragma unroll
    for (int e = 0; e < 16; ++e) {
        const int g = wv * 32 + (e & 3) + 8 * (e >> 2) + 4 * h;
        sp[(size_t)g * 64 + bg] = sacc[e] * scale;
    }
}

__global__ __launch_bounds__(256)
void caps_reduce1(const float* __restrict__ sp, float* __restrict__ s2)
{
    const int e  = blockIdx.x * 256 + threadIdx.x;
    const int pg = blockIdx.y;
    const float* p0 = sp + (size_t)pg * 16 * SELEM + e;
    float a = 0.0f;
#pragma unroll 8
    for (int p = 0; p < 16; ++p) a += p0[(size_t)p * SELEM];
    s2[pg * SELEM + e] = a;
}

__global__ __launch_bounds__(64)
void caps_reduce2T(const float* __restrict__ src, float* __restrict__ vsumT,
                   float* __restrict__ out, int mode)
{
    const int c = blockIdx.x;
    const int b = threadIdx.x;
    float a[16];
#pragma unroll
    for (int o = 0; o < 16; ++o) a[o] = 0.0f;
    for (int p = 0; p < 8; ++p)
#pragma unroll
        for (int o = 0; o < 16; ++o)
            a[o] += src[(size_t)p * SELEM + c * 1024 + o * 64 + b];
    float sq = 0.0f;
#pragma unroll
    for (int o = 0; o < 16; ++o) sq += a[o] * a[o];
    const float n  = sqrtf(sq);
    const float sc = sq / (1.0f + sq) / (n + 1e-8f);
    if (mode == 2) {
#pragma unroll
        for (int o = 0; o < 16; ++o)
            out[(size_t)b * 512 + c * 16 + o] = a[o] * sc;
    } else if (mode == 0) {
#pragma unroll
        for (int o = 0; o < 16; ++o)
            vsumT[c * 1024 + o * 64 + b] = a[o] * sc;
    } else {
#pragma unroll
        for (int o = 0; o < 16; ++o)
            vsumT[c * 1024 + o * 64 + b] += a[o] * sc;
    }
}

// ---------------------------------------------------------------- launcher
extern "C" void kernel_launch(void* const* d_in, const int* in_sizes, int n_in,
                              void* d_out, int out_size, void* d_ws, size_t ws_size,
                              hipStream_t stream)
{
    const float* x = (const float*)d_in[0];          // [64, 4608, 16]
    const float* W = (const float*)d_in[1];          // [4608, 32, 16, 16]
    float* out = (float*)d_out;                      // [64, 32, 16]

    const size_t WPB = (size_t)R_ * 16 * 64 * 8 * sizeof(_Float16);  // 75,497,472
    const size_t XAB = (size_t)R_ * 64 * 16 * sizeof(_Float16);      //  9,437,184
    const size_t SPB = (size_t)NBLK * SELEM * sizeof(float);         // 16,777,216
    const size_t S2B = (size_t)8 * SELEM * sizeof(float);
    const size_t VSB = (size_t)SELEM * sizeof(float);
    char* wsc = (char*)d_ws;

    if (ws_size < WPB + XAB + SPB + S2B + VSB) return;   // harness ws is larger

    _Float16* wp  = (_Float16*)wsc;
    _Float16* xa  = (_Float16*)(wsc + WPB);
    float* s_part = (float*)(wsc + WPB + XAB);
    float* s2     = (float*)(wsc + WPB + XAB + SPB);
    float* vsumT  = (float*)(wsc + WPB + XAB + SPB + S2B);

    // ---- preferred: one cooperative kernel ----
    {
        const float* xA = x; const float* wA = W;
        _Float16* wpA = wp; float* spA = s_part; float* s2A = s2;
        float* vsA = vsumT; float* outA = out;
        void* cargs[] = { (void*)&xA, (void*)&wA, (void*)&wpA, (void*)&spA,
                          (void*)&s2A, (void*)&vsA, (void*)&outA };
        hipError_t cerr = hipLaunchCooperativeKernel((const void*)caps_fused,
                                                     dim3(256), dim3(1024),
                                                     cargs, 0, stream);
        if (cerr == hipSuccess) return;
        (void)hipGetLastError();                  // clear, fall through
    }

    // ---- fallback: round-14 multi-kernel path ----
    caps_prep<<<576, 512, 0, stream>>>(x, xa);

    caps_mfma<true ><<<256, 1024, 0, stream>>>(xa, W, wp, nullptr, s_part);
    caps_reduce1<<<dim3(128, 8), 256, 0, stream>>>(s_part, s2);
    caps_reduce2T<<<32, 64, 0, stream>>>(s2, vsumT, nullptr, 0);

    caps_mfma<false><<<256, 1024, 0, stream>>>(xa, W, wp, vsumT, s_part);
    caps_reduce1<<<dim3(128, 8), 256, 0, stream>>>(s_part, s2);
    caps_reduce2T<<<32, 64, 0, stream>>>(s2, vsumT, nullptr, 1);

    caps_mfma<false><<<256, 1024, 0, stream>>>(xa, W, wp, vsumT, s_part);
    caps_reduce1<<<dim3(128, 8), 256, 0, stream>>>(s_part, s2);
    caps_reduce2T<<<32, 64, 0, stream>>>(s2, vsumT, out, 2);
}

// Round 17
// 138.759 us; speedup vs baseline: 7.9417x; 7.9417x over previous
//
#include <hip/hip_runtime.h>
#include <math.h>

// Capsule dynamic routing, B=64, R=4608, C=32, Din=Dout=16, 3 iters.
// b-logits are linear in v -> keep only vsum; u_hat recomputed per pass via
// mfma_f32_32x32x16_f16 (K=16==Din, A=Wfrag, B=xfrag -> D[(c,o)][b]).
//
// Round-17: revert r16's cooperative fusion (grid.sync ~100us each -> 8x
// regression) back to the r14 champion structure, but graft the two r16
// components that PASSED validation:
//  - fused x f32 -> swizzled-LDS conversion inside each pass (prep kernel,
//    xa buffer, and one boundary deleted; x is L3-resident after pass 1);
//  - single-kernel reduction (32 blk x 1024 thr sums all 128 partials
//    directly + in-LDS squash) replacing reduce1+reduce2T (3 dispatches and
//    the s2 round-trip deleted).
// Pass bodies byte-identical to round 14 (measured best: 139.6us).
// Dispatches: 10 -> 6.

#define B_    64
#define R_    4608
#define C_    32
#define RB    36
#define NBLK  (R_ / RB)      // 128
#define SELEM 32768          // 512 * 64

typedef _Float16 half8  __attribute__((ext_vector_type(8)));
typedef _Float16 half4v __attribute__((ext_vector_type(4)));
typedef _Float16 half2v __attribute__((ext_vector_type(2)));
typedef float    f32x16 __attribute__((ext_vector_type(16)));

// ------------------------------------------------------------- MFMA pass
// D = mfma(A=Wfrag, B=xfrag): D[row=(c,o)][col=b_loc].
// lane: col b_loc = lane&31; rows (regs): R(e,h) = (e&3)+8*(e>>2)+4*h.
// wave wv owns N-tile wv: c = 2*wv+(l31>>4), o = l31&15, k = 8h+e.
// XCD-pairing: xcd = D%8; s = D/8; chunk = (s>>1)*8+xcd; bh = s&1.
// x tile loaded f32 -> converted -> swizzled LDS in-kernel (r16-verified).
// FIRST: fused W f32 fragment gather per r (no in-loop barriers), MFMA,
// stores frag to wp (bh==0). Non-FIRST: r14's 2-r batched loop.
template<bool FIRST>
__global__ __launch_bounds__(1024, 4)
void caps_mfma(const float* __restrict__ x, const float* __restrict__ Wg,
               _Float16* __restrict__ wp, const float* __restrict__ vsumT,
               float* __restrict__ sdst)
{
    __shared__ _Float16 xalds[RB * 512];      // 36 KB
    __shared__ float tc_lds[2][32][33];

    const int D     = blockIdx.x;
    const int xcd   = D & 7;
    const int slot  = D >> 3;
    const int chunk = (slot >> 1) * 8 + xcd;  // 0..127 (bijective pairing)
    const int bh    = slot & 1;

    const int tid  = threadIdx.x;
    const int lane = tid & 63;
    const int wv   = tid >> 6;                // 0..15 = N-tile
    const int h    = lane >> 5;
    const int l31  = lane & 31;
    const int r0   = chunk * RB;
    const int bg   = bh * 32 + l31;

    // ---- x tile -> swizzled LDS (f32 read, f16 convert; r16-verified) ----
    // logical bytes P = rloc*1024 + b_loc*32 + i*2; stored at
    // f(P) = P ^ (((P>>7)&7)<<4) — same involution the avoff reader uses.
    {
        const float* xbase = x + (size_t)(bh * 32) * (R_ * 16);
        for (int i = tid; i < RB * 32 * 4; i += 1024) {   // 4608 16B-chunks
            const int b_   = i / (RB * 4);
            const int rem  = i - b_ * (RB * 4);
            const int rloc = rem >> 2;
            const int part = rem & 3;
            const float4 v = *(const float4*)(xbase + (size_t)b_ * (R_ * 16)
                                              + (size_t)(r0 + rloc) * 16 + part * 4);
            half4v f;
            f[0] = (_Float16)v.x; f[1] = (_Float16)v.y;
            f[2] = (_Float16)v.z; f[3] = (_Float16)v.w;
            const int P = rloc * 1024 + b_ * 32 + part * 8;
            const int A = P ^ (((P >> 7) & 7) << 4);
            *(half4v*)((char*)xalds + A) = f;
        }
    }

    f32x16 sacc, zf;
#pragma unroll
    for (int k = 0; k < 16; ++k) { sacc[k] = 0.f; zf[k] = 0.f; }

    half2v vh[8];
    if (!FIRST) {
#pragma unroll
        for (int e = 0; e < 16; ++e) {
            const int g = wv * 32 + (e & 3) + 8 * (e >> 2) + 4 * h;
            vh[e >> 1][e & 1] = (_Float16)vsumT[(size_t)g * 64 + bg];
        }
    }

    __syncthreads();

    const int avoff = ((l31 << 5) + (h << 4)) ^ (((l31 >> 2) & 7) << 4);

    // W-fragment addressing (identical indices to the validated wprep)
    const int c_ = 2 * wv + (l31 >> 4);
    const int o_ = l31 & 15;
#define WGATHER(dst, r)                                                           \
    do {                                                                          \
        const float* ws_ = Wg + (((size_t)(r) * 32 + c_) * 16 + 8 * h) * 16 + o_; \
        _Pragma("unroll")                                                         \
        for (int e_ = 0; e_ < 8; ++e_) dst[e_] = (_Float16)ws_[e_ * 16];          \
    } while (0)

    const size_t wstride = 16 * 64 * 8;       // f16 per r

    if (FIRST) {
        half8 bc;
        WGATHER(bc, r0);
#pragma unroll 1
        for (int t = 0; t < RB; ++t) {
            const half8 av = *(const half8*)((const char*)xalds + t * 1024 + avoff);
            sacc = __builtin_amdgcn_mfma_f32_32x32x16_f16(bc, av, sacc, 0, 0, 0);
            if (bh == 0)
                *(half8*)(wp + (((size_t)(r0 + t) * 16 + wv) * 64 + lane) * 8) = bc;
            if (t + 1 < RB) WGATHER(bc, r0 + t + 1);
        }
    } else {
        const _Float16* wpb = wp + ((size_t)wv * 64 + lane) * 8;
        half8 bc0 = *(const half8*)(wpb + (size_t)(r0    ) * wstride);
        half8 bc1 = *(const half8*)(wpb + (size_t)(r0 + 1) * wstride);

#pragma unroll 1
        for (int t = 0; t < RB; t += 2) {
            const half8 av0 = *(const half8*)((const char*)xalds + (t    ) * 1024 + avoff);
            const half8 av1 = *(const half8*)((const char*)xalds + (t + 1) * 1024 + avoff);

            const f32x16 u0 = __builtin_amdgcn_mfma_f32_32x32x16_f16(bc0, av0, zf, 0, 0, 0);
            const f32x16 u1 = __builtin_amdgcn_mfma_f32_32x32x16_f16(bc1, av1, zf, 0, 0, 0);

            // prefetch next pair's W-frags (clamped tail reload harmless)
            const int tn = (t + 2 < RB) ? (t + 2) : t;
            bc0 = *(const half8*)(wpb + (size_t)(r0 + tn    ) * wstride);
            bc1 = *(const half8*)(wpb + (size_t)(r0 + tn + 1) * wstride);

            // ---- logits for BOTH r: in-register o-reduce + half-swap fold
            {
                float a0 = 0.f, a1 = 0.f, b0 = 0.f, b1 = 0.f;
#pragma unroll
                for (int e2 = 0; e2 < 4; ++e2) {
                    a0 += u0[2 * e2]         * (float)vh[e2][0];
                    a0 += u0[2 * e2 + 1]     * (float)vh[e2][1];
                    a1 += u0[8 + 2 * e2]     * (float)vh[4 + e2][0];
                    a1 += u0[8 + 2 * e2 + 1] * (float)vh[4 + e2][1];
                    b0 += u1[2 * e2]         * (float)vh[e2][0];
                    b0 += u1[2 * e2 + 1]     * (float)vh[e2][1];
                    b1 += u1[8 + 2 * e2]     * (float)vh[4 + e2][0];
                    b1 += u1[8 + 2 * e2 + 1] * (float)vh[4 + e2][1];
                }
                a0 += __shfl_xor(a0, 32);
                a1 += __shfl_xor(a1, 32);
                b0 += __shfl_xor(b0, 32);
                b1 += __shfl_xor(b1, 32);
                if (h == 0) {
                    tc_lds[0][2 * wv    ][l31] = a0;
                    tc_lds[0][2 * wv + 1][l31] = a1;
                    tc_lds[1][2 * wv    ][l31] = b0;
                    tc_lds[1][2 * wv + 1][l31] = b1;
                }
            }
            __syncthreads();

            // ---- softmax over c, all 1024 threads: (rr, c-pair a_, b2);
            // in-place (each entry read+written by exactly one thread)
            {
                const int rr   = tid >> 9;
                const int tid5 = tid & 511;
                const int a_   = tid5 & 15;
                const int b2   = tid5 >> 4;
                const float tA = tc_lds[rr][2 * a_][b2];
                const float tB = tc_lds[rr][2 * a_ + 1][b2];
                float m = fmaxf(tA, tB);
                m = fmaxf(m, __shfl_xor(m, 1));
                m = fmaxf(m, __shfl_xor(m, 2));
                m = fmaxf(m, __shfl_xor(m, 4));
                m = fmaxf(m, __shfl_xor(m, 8));
                const float eA = __expf(tA - m);
                const float eB = __expf(tB - m);
                float zs = eA + eB;
                zs += __shfl_xor(zs, 1);
                zs += __shfl_xor(zs, 2);
                zs += __shfl_xor(zs, 4);
                zs += __shfl_xor(zs, 8);
                const float inv = 1.0f / zs;
                tc_lds[rr][2 * a_][b2]     = eA * inv;
                tc_lds[rr][2 * a_ + 1][b2] = eB * inv;
            }
            __syncthreads();

            // ---- accumulate both r: sacc += c_ij * u
            {
                const float c00 = tc_lds[0][2 * wv    ][l31];
                const float c01 = tc_lds[0][2 * wv + 1][l31];
                const float c10 = tc_lds[1][2 * wv    ][l31];
                const float c11 = tc_lds[1][2 * wv + 1][l31];
#pragma unroll
                for (int e = 0; e < 8; ++e)
                    sacc[e] += c00 * u0[e] + c10 * u1[e];
#pragma unroll
                for (int e = 8; e < 16; ++e)
                    sacc[e] += c01 * u0[e] + c11 * u1[e];
            }
        }
    }
#undef WGATHER

    // epilogue: transposed partial store sT[g][b] (coalesced over b)
    const float scale = FIRST ? 0.03125f : 1.0f;
    float* sp = sdst + ((size_t)chunk << 15);
#pragma unroll
    for (int e = 0; e < 16; ++e) {
        const int g = wv * 32 + (e & 3) + 8 * (e >> 2) + 4 * h;
        sp[(size_t)g * 64 + bg] = sacc[e] * scale;
    }
}

// --------------------------------------------- fused reduction + squash
// 32 blocks (c) x 1024 threads (o = tid>>6, b = tid&63): sum all 128
// partials directly (coalesced over b), squash via in-LDS o-reduction.
// mode 0: vsumT = v; 1: vsumT += v; 2: out[b][c][o] = v.  (r16-verified)
__global__ __launch_bounds__(1024)
void caps_reduce(const float* __restrict__ sp, float* __restrict__ vsumT,
                 float* __restrict__ out, int mode)
{
    __shared__ float sq_lds[16][64];
    const int c   = blockIdx.x;
    const int tid = threadIdx.x;

    float a = 0.f;
#pragma unroll 8
    for (int p = 0; p < NBLK; ++p)
        a += sp[(size_t)p * SELEM + c * 1024 + tid];

    sq_lds[tid >> 6][tid & 63] = a * a;
    __syncthreads();
    float sq = 0.f;
#pragma unroll
    for (int o = 0; o < 16; ++o) sq += sq_lds[o][tid & 63];
    const float n = sqrtf(sq);
    const float v = a * (sq / (1.0f + sq) / (n + 1e-8f));

    if (mode == 0)      vsumT[c * 1024 + tid] = v;
    else if (mode == 1) vsumT[c * 1024 + tid] += v;
    else                out[(size_t)(tid & 63) * 512 + c * 16 + (tid >> 6)] = v;
}

// ---------------------------------------------------------------- launcher
extern "C" void kernel_launch(void* const* d_in, const int* in_sizes, int n_in,
                              void* d_out, int out_size, void* d_ws, size_t ws_size,
                              hipStream_t stream)
{
    const float* x = (const float*)d_in[0];          // [64, 4608, 16]
    const float* W = (const float*)d_in[1];          // [4608, 32, 16, 16]
    float* out = (float*)d_out;                      // [64, 32, 16]

    const size_t WPB = (size_t)R_ * 16 * 64 * 8 * sizeof(_Float16);  // 75,497,472
    const size_t SPB = (size_t)NBLK * SELEM * sizeof(float);         // 16,777,216
    const size_t VSB = (size_t)SELEM * sizeof(float);                //    131,072
    char* wsc = (char*)d_ws;
    if (ws_size < WPB + SPB + VSB) return;           // harness ws is larger

    _Float16* wp  = (_Float16*)wsc;
    float* s_part = (float*)(wsc + WPB);
    float* vsumT  = (float*)(wsc + WPB + SPB);

    caps_mfma<true ><<<256, 1024, 0, stream>>>(x, W, wp, nullptr, s_part);
    caps_reduce<<<32, 1024, 0, stream>>>(s_part, vsumT, nullptr, 0);

    caps_mfma<false><<<256, 1024, 0, stream>>>(x, W, wp, vsumT, s_part);
    caps_reduce<<<32, 1024, 0, stream>>>(s_part, vsumT, nullptr, 1);

    caps_mfma<false><<<256, 1024, 0, stream>>>(x, W, wp, vsumT, s_part);
    caps_reduce<<<32, 1024, 0, stream>>>(s_part, vsumT, out, 2);
}